// Round 1
// baseline (127.734 us; speedup 1.0000x reference)
//
#include <hip/hip_runtime.h>

// KAN Convolutional Layer, fp32, MI355X.
// Shapes: x (16,32,64,64), base_w (8,9), spline_w (8,9,8), spline_scaler (8,9)
// out (16, 32*8, 62, 62).
//
// Strategy: per (b,c)-plane strips of 4 output rows. Stage per-pixel features
// (silu(x) + dense 8-wide cubic B-spline basis) into LDS once per pixel
// (9x reuse across the 3x3 window), then an 9-in/8-out 3x3 conv whose weight
// operands are wave-uniform scalar loads.

constexpr int Hh = 64, Ww = 64;
constexpr int Ho = 62, Wo = 62;
constexpr int L = Ho * Wo;          // 3844
constexpr int NC = 8;               // n_convs
constexpr int TH = 4;               // output rows per block
constexpr int NSTRIP = 16;          // ceil(62/4)
constexpr int PXS = (TH + 2) * Ww;  // 384 staged pixels (max)

__global__ __launch_bounds__(256)
void kan_conv_kernel(const float* __restrict__ x,
                     const float* __restrict__ base_w,
                     const float* __restrict__ spline_w,
                     const float* __restrict__ spline_scaler,
                     float* __restrict__ out)
{
    // fsh[0][px]        = silu(x)
    // fsh[1+s][px]      = basis_s(x), s = 0..7   (plane stride 384 floats:
    //                      1536 B == 0 mod 128 -> conflict-free scatter/reads)
    __shared__ float fsh[9 * PXS];

    const int strip = blockIdx.x & (NSTRIP - 1);
    const int bc    = blockIdx.x >> 4;           // 0..511  (b*32 + c)
    const int r0    = strip * TH;
    const int rows_out = (r0 + TH <= Ho) ? TH : (Ho - r0);   // 4, last strip 2
    const int npx   = (rows_out + 2) * Ww;
    const int nloc  = rows_out * Wo;

    // ---- zero the 8 basis planes (scatter below only writes <=4 taps) ----
    for (int i = threadIdx.x; i < 8 * PXS; i += 256) fsh[PXS + i] = 0.0f;
    __syncthreads();

    // ---- feature stage: one pass over staged pixels ----
    const float* xp = x + (size_t)bc * (Hh * Ww) + (size_t)r0 * Ww;
    for (int p = threadIdx.x; p < npx; p += 256) {
        float v = xp[p];

        // silu
        float sv = v / (1.0f + __expf(-v));
        fsh[p] = sv;

        // uniform cubic B-spline, closed form.
        // grid: knot[i] = (i-3)*0.4 - 1, i = 0..11  ->  u = (v+2.2)*2.5
        float u  = (v + 2.2f) * 2.5f;
        float fj = floorf(u);
        float t  = u - fj;          // in [0,1)
        int   j  = (int)fj;         // interval index; valid splines need j in [0,10]
        float om = 1.0f - t;
        float t2 = t * t;
        float w3 = t * t2 * (1.0f / 6.0f);
        float w0 = om * om * om * (1.0f / 6.0f);
        float w1 = fmaf(t2, fmaf(t, 0.5f, -1.0f), 2.0f / 3.0f); // (3t^3-6t^2+4)/6
        float w2 = 1.0f - w0 - w1 - w3;                          // partition of unity

        // scatter the 4 non-zero taps into basis planes jm3..jm3+3 (clipped to [0,7]).
        // j outside [0,10] -> no tap lands in [0,7] -> contributes zero, matching ref.
        int jm3 = j - 3;
        if ((unsigned)(jm3 + 0) < 8u) fsh[(1 + jm3 + 0) * PXS + p] = w0;
        if ((unsigned)(jm3 + 1) < 8u) fsh[(1 + jm3 + 1) * PXS + p] = w1;
        if ((unsigned)(jm3 + 2) < 8u) fsh[(1 + jm3 + 2) * PXS + p] = w2;
        if ((unsigned)(jm3 + 3) < 8u) fsh[(1 + jm3 + 3) * PXS + p] = w3;
    }
    __syncthreads();

    // ---- conv stage: one thread per output location, all 8 convs ----
    if ((int)threadIdx.x < nloc) {
        const int r = threadIdx.x / Wo;
        const int c = threadIdx.x - r * Wo;

        float acc[NC];
#pragma unroll
        for (int n = 0; n < NC; n++) acc[n] = 0.0f;

#pragma unroll
        for (int kh = 0; kh < 3; kh++) {
#pragma unroll
            for (int kw = 0; kw < 3; kw++) {
                const int k  = kh * 3 + kw;
                const int px = (r + kh) * Ww + (c + kw);

                float f0 = fsh[px];
                float fb[8];
#pragma unroll
                for (int s = 0; s < 8; s++) fb[s] = fsh[(1 + s) * PXS + px];

#pragma unroll
                for (int n = 0; n < NC; n++) {
                    // spline dot (weights are wave-uniform -> scalar loads)
                    float d = fb[0] * spline_w[(n * 9 + k) * 8 + 0];
#pragma unroll
                    for (int s = 1; s < 8; s++)
                        d = fmaf(fb[s], spline_w[(n * 9 + k) * 8 + s], d);
                    acc[n] = fmaf(spline_scaler[n * 9 + k], d, acc[n]);
                    acc[n] = fmaf(f0, base_w[n * 9 + k], acc[n]);
                }
            }
        }

        const size_t ob = (size_t)bc * NC * L + (size_t)(r0 + r) * Wo + c;
#pragma unroll
        for (int n = 0; n < NC; n++) out[ob + (size_t)n * L] = acc[n];
    }
}

extern "C" void kernel_launch(void* const* d_in, const int* in_sizes, int n_in,
                              void* d_out, int out_size, void* d_ws, size_t ws_size,
                              hipStream_t stream) {
    const float* x   = (const float*)d_in[0];
    const float* bw  = (const float*)d_in[1];
    const float* sw  = (const float*)d_in[2];
    const float* scl = (const float*)d_in[3];
    float* out = (float*)d_out;

    const int planes = in_sizes[0] / (Hh * Ww);   // B*C = 512
    dim3 grid(planes * NSTRIP);                   // 8192 blocks
    kan_conv_kernel<<<grid, 256, 0, stream>>>(x, bw, sw, scl, out);
}